// Round 1
// baseline (61.232 us; speedup 1.0000x reference)
//
#include <hip/hip_runtime.h>

// Problem constants (fixed by the reference's setup_inputs):
//   B=32, C=1, H=W=112, O=64, KH=KW=5, stride=1 -> oh=ow=108
constexpr int KH = 5, KW = 5;
constexpr int O  = 64;
constexpr int D  = KH * KW;          // 25
constexpr int H  = 112, W = 112;
constexpr int OH = H - KH + 1;       // 108
constexpr int OW = W - KW + 1;       // 108
constexpr int P  = OH * OW;          // 11664

__global__ __launch_bounds__(256) void rbf_conv_kernel(
    const float* __restrict__ gin, const float* __restrict__ rin,
    const float* __restrict__ gw,  const float* __restrict__ rw,
    const float* __restrict__ stdp, float* __restrict__ out, int B)
{
    // Per-filter weight norms, computed once per block (tiny).
    __shared__ float s_w2g[O], s_w2r[O];
    const int t = threadIdx.x;
    if (t < O) {
        float sg = 0.f, sr = 0.f;
        #pragma unroll
        for (int k = 0; k < D; ++k) {
            float a = gw[t * D + k]; sg = fmaf(a, a, sg);
            float b = rw[t * D + k]; sr = fmaf(b, b, sr);
        }
        s_w2g[t] = sg;
        s_w2r[t] = sr;
    }
    __syncthreads();

    const int idx   = blockIdx.x * blockDim.x + t;
    const int total = B * P;
    if (idx >= total) return;

    const int b = idx / P;
    const int p = idx - b * P;
    const int y = p / OW;
    const int x = p - y * OW;

    // Load the 5x5 patch for both images into registers; accumulate |a|^2.
    const float* gb = gin + (b * H + y) * W + x;
    const float* rb = rin + (b * H + y) * W + x;
    float ga[D], ra[D];
    float a2g = 0.f, a2r = 0.f;
    #pragma unroll
    for (int i = 0; i < KH; ++i) {
        #pragma unroll
        for (int j = 0; j < KW; ++j) {
            float g = gb[i * W + j]; ga[i * KW + j] = g; a2g = fmaf(g, g, a2g);
            float r = rb[i * W + j]; ra[i * KW + j] = r; a2r = fmaf(r, r, a2r);
        }
    }

    const float s    = stdp[0];
    const float ninv = -1.0f / (2.0f * s * s);
    float* ob = out + (size_t)b * O * P + p;

    // Loop over output channels; weight reads are wave-uniform -> s_loads.
    for (int o = 0; o < O; ++o) {
        float dg = 0.f, dr = 0.f;
        #pragma unroll
        for (int k = 0; k < D; ++k) {
            dg = fmaf(ga[k], gw[o * D + k], dg);
            dr = fmaf(ra[k], rw[o * D + k], dr);
        }
        float d2g = fmaxf(a2g + s_w2g[o] - 2.0f * dg, 0.f);
        float d2r = fmaxf(a2r + s_w2r[o] - 2.0f * dr, 0.f);
        float dist = __fsqrt_rn(d2g) + __fsqrt_rn(d2r);
        ob[(size_t)o * P] = __expf(ninv * dist * dist);
    }
}

extern "C" void kernel_launch(void* const* d_in, const int* in_sizes, int n_in,
                              void* d_out, int out_size, void* d_ws, size_t ws_size,
                              hipStream_t stream) {
    const float* gin  = (const float*)d_in[0];
    const float* rin  = (const float*)d_in[1];
    const float* gw   = (const float*)d_in[2];
    const float* rw   = (const float*)d_in[3];
    const float* stdp = (const float*)d_in[4];
    float* out = (float*)d_out;

    const int B = in_sizes[0] / (H * W);   // 32
    const int total = B * P;
    const int block = 256;
    const int grid  = (total + block - 1) / block;

    rbf_conv_kernel<<<grid, block, 0, stream>>>(gin, rin, gw, rw, stdp, out, B);
}